// Round 12
// baseline (432.523 us; speedup 1.0000x reference)
//
#include <hip/hip_runtime.h>
#include <hip/hip_bf16.h>

#define NN   20000
#define NE   320000
#define EAD  8
#define DIN  16
#define DOUT 16
#define HH   256      // DIN*DOUT
#define SLOPE 0.01f
#define EPB  64       // edges per block
#define MPS  17       // msg partial padded stride (floats)

typedef __attribute__((ext_vector_type(8))) short bf16x8;   // 8 bf16 = 4 VGPRs
typedef __attribute__((ext_vector_type(4))) float f32x4;    // MFMA C/D

// leaky(v) = max(v, 0.01*v)  (valid because slope < 1)
__device__ __forceinline__ float leakyf(float v) { return fmaxf(v, SLOPE * v); }

// hw-packed fp32x2 -> bf16x2 (v_cvt_pk_bf16_f32, RNE); union pun (bit_cast
// rejects non-trivially-copyable __hip_bfloat162)
__device__ __forceinline__ unsigned int pk2bf(float a, float b) {
    union { __hip_bfloat162 h2; unsigned int u; } cv;
    cv.h2 = __float22bfloat162_rn(float2{a, b});
    return cv.u;
}
// scalar fp32 -> bf16 (prep only)
__device__ __forceinline__ unsigned short f2bf(float f) {
    unsigned int u = __builtin_bit_cast(unsigned int, f);
    u += 0x7FFFu + ((u >> 16) & 1u);
    return (unsigned short)(u >> 16);
}

// swizzle: XOR u16-index bits 4-5 with t&3 (same as r9; ~10% tax, not the wall)
#define HSWZ(t, idx) ((idx) ^ (((t) & 3) << 4))

// prep: w2 -> w2T[c][j] bf16 (both layers), w1 -> w1T[j][k] bf16 (both layers)
__global__ void prep_kernel(const float* __restrict__ w2_0, const float* __restrict__ w2_1,
                            const float* __restrict__ w1_0, const float* __restrict__ w1_1,
                            unsigned short* __restrict__ w2T0, unsigned short* __restrict__ w2T1,
                            unsigned short* __restrict__ w1T0, unsigned short* __restrict__ w1T1)
{
    int idx = blockIdx.x * 256 + threadIdx.x;
    if (idx < HH * HH) {
        int c = idx >> 8, j = idx & 255;
        w2T0[idx] = f2bf(w2_0[j * HH + c]);
        w2T1[idx] = f2bf(w2_1[j * HH + c]);
    }
    if (idx < HH * EAD) {
        int j = idx >> 3, k = idx & 7;
        w1T0[idx] = f2bf(w1_0[k * HH + j]);
        w1T1[idx] = f2bf(w1_1[k * HH + j]);
    }
}

// Fused NNConv message pass (MFMA), 3-barrier, h_us (32 KB exactly) reused for
// msg partials; no other LDS -> 5 blocks/CU.
template<int COUNT>
__global__ __launch_bounds__(256, 5)
void edge_kernel(const float* __restrict__ x,      // [NN,16]
                 const int*   __restrict__ esrc,   // [NE]
                 const int*   __restrict__ edst,   // [NE]
                 const float* __restrict__ ea,     // [NE,8]
                 const unsigned short* __restrict__ w1T, // [256 j][8 k] bf16
                 const float* __restrict__ b1,     // [256]
                 const unsigned short* __restrict__ w2T, // [256 c][256 j] bf16
                 const float* __restrict__ b2,     // [256]
                 float* __restrict__ agg,          // [NN,16]
                 float* __restrict__ cnt)          // [NN]
{
    __shared__ __align__(16) unsigned short h_us[EPB * HH];  // 32768 B exactly

    const int tid = threadIdx.x;
    const int e0  = blockIdx.x * EPB;
    const int w   = tid >> 6;   // wave 0..3
    const int ln  = tid & 63;
    const int lo  = ln & 15;
    const int g4  = ln >> 4;    // 0..3

    // hoist phase-2 ks=0 B-frags (w2T, L2-resident) above phase-1
    const unsigned short* bbase = w2T + (size_t)(64 * w + lo) * HH + 8 * g4;
    bf16x8 bcur[4], bnxt[4];
    #pragma unroll
    for (int nt = 0; nt < 4; ++nt) bcur[nt] = *(const bf16x8*)(bbase + nt * 16 * HH);

    // ---- phase 1 (transposed): hT[j][t] = leaky(sum_k w1T[j][k] ea[t][k] + b1[j]) ----
    bf16x8 zero8;
    #pragma unroll
    for (int k = 0; k < 8; ++k) zero8[k] = 0;

    bf16x8 aW[4], bE[4];   // A = w1 rows (j), B = ea rows (t); K padded 8->32
    #pragma unroll
    for (int q = 0; q < 4; ++q) { aW[q] = zero8; bE[q] = zero8; }

    if (ln < 16) {  // g4==0 lanes carry k=0..7; others zero
        #pragma unroll
        for (int jj = 0; jj < 4; ++jj)
            aW[jj] = *(const bf16x8*)(w1T + ((4 * w + jj) * 16 + lo) * EAD);
        #pragma unroll
        for (int tb = 0; tb < 4; ++tb) {
            const float4* p = (const float4*)(ea + (size_t)(e0 + 16 * tb + lo) * EAD);
            float4 a0 = p[0], a1 = p[1];       // vectorized 2x16B row load
            union { bf16x8 v8; unsigned int u[4]; } uv;
            uv.u[0] = pk2bf(a0.x, a0.y);
            uv.u[1] = pk2bf(a0.z, a0.w);
            uv.u[2] = pk2bf(a1.x, a1.y);
            uv.u[3] = pk2bf(a1.z, a1.w);
            bE[tb] = uv.v8;
        }
    }

    f32x4 hacc[4][4];   // [jj][tb]
    #pragma unroll
    for (int jj = 0; jj < 4; ++jj) {
        float4 bv = *(const float4*)(b1 + (4 * w + jj) * 16 + 4 * g4);  // b1[j0..j0+3]
        f32x4 bi; bi[0] = bv.x; bi[1] = bv.y; bi[2] = bv.z; bi[3] = bv.w;
        #pragma unroll
        for (int tb = 0; tb < 4; ++tb) hacc[jj][tb] = bi;
    }
    #pragma unroll
    for (int jj = 0; jj < 4; ++jj)
        #pragma unroll
        for (int tb = 0; tb < 4; ++tb)
            hacc[jj][tb] = __builtin_amdgcn_mfma_f32_16x16x32_bf16(aW[jj], bE[tb], hacc[jj][tb], 0, 0, 0);

    // leaky + hw cvt_pk pack (4 consecutive j = D rows) -> one b64 store, swizzled
    #pragma unroll
    for (int jj = 0; jj < 4; ++jj) {
        const int j0 = 64 * w + 16 * jj + 4 * g4;
        #pragma unroll
        for (int tb = 0; tb < 4; ++tb) {
            const int t = 16 * tb + lo;
            uint2 pk;
            pk.x = pk2bf(leakyf(hacc[jj][tb][0]), leakyf(hacc[jj][tb][1]));
            pk.y = pk2bf(leakyf(hacc[jj][tb][2]), leakyf(hacc[jj][tb][3]));
            *(uint2*)&h_us[HSWZ(t, t * HH + j0)] = pk;
        }
    }
    __syncthreads();   // barrier 1: h ready

    // ---- phase 2: W = h @ w2 + b2  (M=64 edges, N=256 cols, K=256) ----
    f32x4 acc[4][4];
    #pragma unroll
    for (int nt = 0; nt < 4; ++nt) {
        float bv = b2[64 * w + 16 * nt + lo];
        f32x4 bi; bi[0] = bv; bi[1] = bv; bi[2] = bv; bi[3] = bv;
        #pragma unroll
        for (int mt = 0; mt < 4; ++mt) acc[mt][nt] = bi;
    }
    #pragma unroll
    for (int ks = 0; ks < 8; ++ks) {
        if (ks < 7) {
            #pragma unroll
            for (int nt = 0; nt < 4; ++nt)
                bnxt[nt] = *(const bf16x8*)(bbase + nt * 16 * HH + 32 * (ks + 1));
        }
        bf16x8 af[4];   // lane: h[t=16mt+lo][j=32ks+8g4 .. +8]
        #pragma unroll
        for (int mt = 0; mt < 4; ++mt) {
            int t = 16 * mt + lo;
            af[mt] = *(const bf16x8*)(h_us + HSWZ(t, t * HH + 32 * ks + 8 * g4));
        }
        #pragma unroll
        for (int mt = 0; mt < 4; ++mt)
            #pragma unroll
            for (int nt = 0; nt < 4; ++nt)
                acc[mt][nt] = __builtin_amdgcn_mfma_f32_16x16x32_bf16(af[mt], bcur[nt], acc[mt][nt], 0, 0, 0);
        #pragma unroll
        for (int nt = 0; nt < 4; ++nt) bcur[nt] = bnxt[nt];
    }
    __syncthreads();   // barrier 2: all h reads done -> h_us reusable

    // ---- epilogue: per-wave partial msg into reused h_us region ----
    // lane's col c = 64w+16nt+lo -> i = 4w+nt, o = lo; D row -> t = 16mt+4g4+r
    float* msgp = (float*)h_us;   // [4][EPB][MPS] = 17408 B < 32 KB
    #pragma unroll
    for (int mt = 0; mt < 4; ++mt)
        #pragma unroll
        for (int r = 0; r < 4; ++r) {
            const int t = 16 * mt + 4 * g4 + r;
            const int s = esrc[e0 + t];                 // L1-resident 256B region
            float4 xv = *(const float4*)(x + (size_t)s * DIN + 4 * w);
            float ps = xv.x * acc[mt][0][r] + xv.y * acc[mt][1][r]
                     + xv.z * acc[mt][2][r] + xv.w * acc[mt][3][r];
            msgp[(w * EPB + t) * MPS + lo] = ps;
        }
    __syncthreads();   // barrier 3: msg partials ready

    // ---- tail: sum 4 wave-partials, scatter with global fp32 atomics ----
    {
        const int t = tid >> 2, p = tid & 3;
        const int d = edst[e0 + t];                     // coalesced, L1/L2
        #pragma unroll
        for (int oo = 0; oo < 4; ++oo) {
            const int o = 4 * p + oo;
            float m = msgp[(0 * EPB + t) * MPS + o] + msgp[(1 * EPB + t) * MPS + o]
                    + msgp[(2 * EPB + t) * MPS + o] + msgp[(3 * EPB + t) * MPS + o];
            atomicAdd(&agg[(size_t)d * DOUT + o], m);
        }
        if (COUNT && p == 0) atomicAdd(&cnt[d], 1.0f);
    }
}

// out[n][o] = agg[n][o]/max(cnt,1) + x[n]@root[:,o] + bias[o]  (opt leaky)
// ZERO: re-zero agg after reading (replaces the mid-stream memset)
template<int ZERO>
__global__ void finalize_kernel(float* __restrict__ agg,
                                const float* __restrict__ cnt,
                                const float* __restrict__ xin,
                                const float* __restrict__ root, // [16,16]
                                const float* __restrict__ bias, // [16]
                                float* __restrict__ out,
                                int do_leaky)
{
    int idx = blockIdx.x * blockDim.x + threadIdx.x;
    if (idx >= NN * DOUT) return;
    int n = idx >> 4, o = idx & 15;
    float c = cnt[n];
    c = c > 1.f ? c : 1.f;
    float v = agg[idx] / c;
    if (ZERO) agg[idx] = 0.f;
    #pragma unroll
    for (int i = 0; i < DIN; ++i)
        v += xin[n * DIN + i] * root[i * DOUT + o];
    v += bias[o];
    out[idx] = do_leaky ? leakyf(v) : v;
}

extern "C" void kernel_launch(void* const* d_in, const int* in_sizes, int n_in,
                              void* d_out, int out_size, void* d_ws, size_t ws_size,
                              hipStream_t stream)
{
    const float* x      = (const float*)d_in[0];
    const int*   ei     = (const int*)  d_in[1];
    const float* ea     = (const float*)d_in[2];
    const float* w1_0   = (const float*)d_in[3];
    const float* b1_0   = (const float*)d_in[4];
    const float* w2_0   = (const float*)d_in[5];
    const float* b2_0   = (const float*)d_in[6];
    const float* root_0 = (const float*)d_in[7];
    const float* bias_0 = (const float*)d_in[8];
    const float* w1_1   = (const float*)d_in[9];
    const float* b1_1   = (const float*)d_in[10];
    const float* w2_1   = (const float*)d_in[11];
    const float* b2_1   = (const float*)d_in[12];
    const float* root_1 = (const float*)d_in[13];
    const float* bias_1 = (const float*)d_in[14];

    const int* esrc = ei;
    const int* edst = ei + NE;

    // ws: w2T0|w2T1 (bf16) | w1T0|w1T1 (bf16) | agg | cnt | x1 (f32)
    unsigned short* w2T0 = (unsigned short*)d_ws;
    unsigned short* w2T1 = w2T0 + HH * HH;
    unsigned short* w1T0 = w2T1 + HH * HH;
    unsigned short* w1T1 = w1T0 + HH * EAD;
    float* agg = (float*)(w1T1 + HH * EAD);
    float* cnt = agg + (size_t)NN * DOUT;
    float* x1  = cnt + NN;
    const size_t ws_need = (size_t)((char*)(x1 + (size_t)NN * DIN) - (char*)d_ws);
    if (ws_size < ws_need) return;  // fail clean (absmax), not a GPU fault

    (void)hipMemsetAsync(agg, 0, ((size_t)NN * DOUT + NN) * sizeof(float), stream);
    prep_kernel<<<HH * HH / 256, 256, 0, stream>>>(w2_0, w2_1, w1_0, w1_1,
                                                   w2T0, w2T1, w1T0, w1T1);

    edge_kernel<1><<<NE / EPB, 256, 0, stream>>>(x, esrc, edst, ea,
                                                 w1T0, b1_0, w2T0, b2_0, agg, cnt);
    finalize_kernel<1><<<(NN * DOUT + 255) / 256, 256, 0, stream>>>(agg, cnt, x,
                                                 root_0, bias_0, x1, 1);
    edge_kernel<0><<<NE / EPB, 256, 0, stream>>>(x1, esrc, edst, ea,
                                                 w1T1, b1_1, w2T1, b2_1, agg, cnt);
    finalize_kernel<0><<<(NN * DOUT + 255) / 256, 256, 0, stream>>>(agg, cnt, x1,
                                                 root_1, bias_1, (float*)d_out, 0);
}

// Round 16
// 330.912 us; speedup vs baseline: 1.3071x; 1.3071x over previous
//
#include <hip/hip_runtime.h>
#include <hip/hip_bf16.h>

#define NN   20000
#define NE   320000
#define EAD  8
#define DIN  16
#define DOUT 16
#define HH   256      // DIN*DOUT
#define SLOPE 0.01f
#define EPB  64       // edges per block
#define MPS  17       // msg partial padded stride (floats)

typedef __attribute__((ext_vector_type(8))) short bf16x8;   // 8 bf16 = 4 VGPRs
typedef __attribute__((ext_vector_type(4))) float f32x4;    // MFMA C/D

// leaky(v) = max(v, 0.01*v)  (valid because slope < 1)
__device__ __forceinline__ float leakyf(float v) { return fmaxf(v, SLOPE * v); }

// hw-packed fp32x2 -> bf16x2 (v_cvt_pk_bf16_f32, RNE); union pun (bit_cast
// rejects non-trivially-copyable __hip_bfloat162)
__device__ __forceinline__ unsigned int pk2bf(float a, float b) {
    union { __hip_bfloat162 h2; unsigned int u; } cv;
    cv.h2 = __float22bfloat162_rn(float2{a, b});
    return cv.u;
}
// scalar fp32 -> bf16 (prep only)
__device__ __forceinline__ unsigned short f2bf(float f) {
    unsigned int u = __builtin_bit_cast(unsigned int, f);
    u += 0x7FFFu + ((u >> 16) & 1u);
    return (unsigned short)(u >> 16);
}

// swizzle: XOR u16-index bits 4-5 with t&3 (~10% conflict tax, not the wall)
#define HSWZ(t, idx) ((idx) ^ (((t) & 3) << 4))

// prep: w2 -> w2T[c][j] bf16 (both layers), w1 -> w1T[j][k] bf16 (both layers)
__global__ void prep_kernel(const float* __restrict__ w2_0, const float* __restrict__ w2_1,
                            const float* __restrict__ w1_0, const float* __restrict__ w1_1,
                            unsigned short* __restrict__ w2T0, unsigned short* __restrict__ w2T1,
                            unsigned short* __restrict__ w1T0, unsigned short* __restrict__ w1T1)
{
    int idx = blockIdx.x * 256 + threadIdx.x;
    if (idx < HH * HH) {
        int c = idx >> 8, j = idx & 255;
        w2T0[idx] = f2bf(w2_0[j * HH + c]);
        w2T1[idx] = f2bf(w2_1[j * HH + c]);
    }
    if (idx < HH * EAD) {
        int j = idx >> 3, k = idx & 7;
        w1T0[idx] = f2bf(w1_0[k * HH + j]);
        w1T1[idx] = f2bf(w1_1[k * HH + j]);
    }
}

// Fused NNConv message pass (MFMA), 3-barrier, h_us reused for msg partials.
// launch_bounds(256,4): VGPR budget 128/wave -> no spills (r12 lesson: (256,5)
// cut to ~102 and spilled 300+ MB of scratch traffic per dispatch).
template<int COUNT>
__global__ __launch_bounds__(256, 4)
void edge_kernel(const float* __restrict__ x,      // [NN,16]
                 const int*   __restrict__ esrc,   // [NE]
                 const int*   __restrict__ edst,   // [NE]
                 const float* __restrict__ ea,     // [NE,8]
                 const unsigned short* __restrict__ w1T, // [256 j][8 k] bf16
                 const float* __restrict__ b1,     // [256]
                 const unsigned short* __restrict__ w2T, // [256 c][256 j] bf16
                 const float* __restrict__ b2,     // [256]
                 float* __restrict__ agg,          // [NN,16]
                 float* __restrict__ cnt)          // [NN]
{
    __shared__ __align__(16) unsigned short h_us[EPB * HH];  // 32 KB; reused as msg partials
    __shared__ int ssrc[EPB];
    __shared__ int sdst[EPB];
    // 33280 B -> 4 blocks/CU

    const int tid = threadIdx.x;
    const int e0  = blockIdx.x * EPB;
    const int w   = tid >> 6;   // wave 0..3
    const int ln  = tid & 63;
    const int lo  = ln & 15;
    const int g4  = ln >> 4;    // 0..3

    if (tid < EPB) {
        ssrc[tid] = esrc[e0 + tid];
        sdst[tid] = edst[e0 + tid];
    }

    // hoist phase-2 ks=0 B-frags (w2T, L2-resident) above phase-1
    const unsigned short* bbase = w2T + (size_t)(64 * w + lo) * HH + 8 * g4;
    bf16x8 bcur[4], bnxt[4];
    #pragma unroll
    for (int nt = 0; nt < 4; ++nt) bcur[nt] = *(const bf16x8*)(bbase + nt * 16 * HH);

    // ---- phase 1 (transposed): hT[j][t] = leaky(sum_k w1T[j][k] ea[t][k] + b1[j]) ----
    bf16x8 zero8;
    #pragma unroll
    for (int k = 0; k < 8; ++k) zero8[k] = 0;

    bf16x8 aW[4], bE[4];   // A = w1 rows (j), B = ea rows (t); K padded 8->32
    #pragma unroll
    for (int q = 0; q < 4; ++q) { aW[q] = zero8; bE[q] = zero8; }

    if (ln < 16) {  // g4==0 lanes carry k=0..7; others zero
        #pragma unroll
        for (int jj = 0; jj < 4; ++jj)
            aW[jj] = *(const bf16x8*)(w1T + ((4 * w + jj) * 16 + lo) * EAD);
        #pragma unroll
        for (int tb = 0; tb < 4; ++tb) {
            const float4* p = (const float4*)(ea + (size_t)(e0 + 16 * tb + lo) * EAD);
            float4 a0 = p[0], a1 = p[1];       // vectorized 2x16B row load
            union { bf16x8 v8; unsigned int u[4]; } uv;
            uv.u[0] = pk2bf(a0.x, a0.y);
            uv.u[1] = pk2bf(a0.z, a0.w);
            uv.u[2] = pk2bf(a1.x, a1.y);
            uv.u[3] = pk2bf(a1.z, a1.w);
            bE[tb] = uv.v8;
        }
    }

    f32x4 hacc[4][4];   // [jj][tb]
    #pragma unroll
    for (int jj = 0; jj < 4; ++jj) {
        float4 bv = *(const float4*)(b1 + (4 * w + jj) * 16 + 4 * g4);  // b1[j0..j0+3]
        f32x4 bi; bi[0] = bv.x; bi[1] = bv.y; bi[2] = bv.z; bi[3] = bv.w;
        #pragma unroll
        for (int tb = 0; tb < 4; ++tb) hacc[jj][tb] = bi;
    }
    #pragma unroll
    for (int jj = 0; jj < 4; ++jj)
        #pragma unroll
        for (int tb = 0; tb < 4; ++tb)
            hacc[jj][tb] = __builtin_amdgcn_mfma_f32_16x16x32_bf16(aW[jj], bE[tb], hacc[jj][tb], 0, 0, 0);

    // leaky + hw cvt_pk pack (4 consecutive j = D rows) -> one b64 store, swizzled
    #pragma unroll
    for (int jj = 0; jj < 4; ++jj) {
        const int j0 = 64 * w + 16 * jj + 4 * g4;
        #pragma unroll
        for (int tb = 0; tb < 4; ++tb) {
            const int t = 16 * tb + lo;
            uint2 pk;
            pk.x = pk2bf(leakyf(hacc[jj][tb][0]), leakyf(hacc[jj][tb][1]));
            pk.y = pk2bf(leakyf(hacc[jj][tb][2]), leakyf(hacc[jj][tb][3]));
            *(uint2*)&h_us[HSWZ(t, t * HH + j0)] = pk;
        }
    }
    __syncthreads();   // barrier 1: h ready

    // ---- phase 2: W = h @ w2 + b2  (M=64 edges, N=256 cols, K=256) ----
    f32x4 acc[4][4];
    #pragma unroll
    for (int nt = 0; nt < 4; ++nt) {
        float bv = b2[64 * w + 16 * nt + lo];
        f32x4 bi; bi[0] = bv; bi[1] = bv; bi[2] = bv; bi[3] = bv;
        #pragma unroll
        for (int mt = 0; mt < 4; ++mt) acc[mt][nt] = bi;
    }
    #pragma unroll
    for (int ks = 0; ks < 8; ++ks) {
        if (ks < 7) {
            #pragma unroll
            for (int nt = 0; nt < 4; ++nt)
                bnxt[nt] = *(const bf16x8*)(bbase + nt * 16 * HH + 32 * (ks + 1));
        }
        bf16x8 af[4];   // lane: h[t=16mt+lo][j=32ks+8g4 .. +8]
        #pragma unroll
        for (int mt = 0; mt < 4; ++mt) {
            int t = 16 * mt + lo;
            af[mt] = *(const bf16x8*)(h_us + HSWZ(t, t * HH + 32 * ks + 8 * g4));
        }
        #pragma unroll
        for (int mt = 0; mt < 4; ++mt)
            #pragma unroll
            for (int nt = 0; nt < 4; ++nt)
                acc[mt][nt] = __builtin_amdgcn_mfma_f32_16x16x32_bf16(af[mt], bcur[nt], acc[mt][nt], 0, 0, 0);
        #pragma unroll
        for (int nt = 0; nt < 4; ++nt) bcur[nt] = bnxt[nt];
    }
    __syncthreads();   // barrier 2: all h reads done -> h_us reusable

    // ---- epilogue: per-wave partial msg into reused h_us region ----
    // lane's col c = 64w+16nt+lo -> i = 4w+nt, o = lo; D row -> t = 16mt+4g4+r
    float* msgp = (float*)h_us;   // [4][EPB][MPS] = 17408 B < 32 KB
    #pragma unroll
    for (int mt = 0; mt < 4; ++mt)
        #pragma unroll
        for (int r = 0; r < 4; ++r) {
            const int t = 16 * mt + 4 * g4 + r;
            float4 xv = *(const float4*)(x + (size_t)ssrc[t] * DIN + 4 * w);  // 16-lane broadcast
            float ps = xv.x * acc[mt][0][r] + xv.y * acc[mt][1][r]
                     + xv.z * acc[mt][2][r] + xv.w * acc[mt][3][r];
            msgp[(w * EPB + t) * MPS + lo] = ps;
        }
    __syncthreads();   // barrier 3: msg partials ready

    // ---- tail: sum 4 wave-partials, scatter with global fp32 atomics ----
    {
        const int t = tid >> 2, p = tid & 3;
        const int d = sdst[t];
        #pragma unroll
        for (int oo = 0; oo < 4; ++oo) {
            const int o = 4 * p + oo;
            float m = msgp[(0 * EPB + t) * MPS + o] + msgp[(1 * EPB + t) * MPS + o]
                    + msgp[(2 * EPB + t) * MPS + o] + msgp[(3 * EPB + t) * MPS + o];
            atomicAdd(&agg[(size_t)d * DOUT + o], m);
        }
        if (COUNT && p == 0) atomicAdd(&cnt[d], 1.0f);
    }
}

// out[n][o] = agg[n][o]/max(cnt,1) + x[n]@root[:,o] + bias[o]  (opt leaky)
// ZERO: re-zero agg after reading (replaces the mid-stream memset)
template<int ZERO>
__global__ void finalize_kernel(float* __restrict__ agg,
                                const float* __restrict__ cnt,
                                const float* __restrict__ xin,
                                const float* __restrict__ root, // [16,16]
                                const float* __restrict__ bias, // [16]
                                float* __restrict__ out,
                                int do_leaky)
{
    int idx = blockIdx.x * blockDim.x + threadIdx.x;
    if (idx >= NN * DOUT) return;
    int n = idx >> 4, o = idx & 15;
    float c = cnt[n];
    c = c > 1.f ? c : 1.f;
    float v = agg[idx] / c;
    if (ZERO) agg[idx] = 0.f;
    #pragma unroll
    for (int i = 0; i < DIN; ++i)
        v += xin[n * DIN + i] * root[i * DOUT + o];
    v += bias[o];
    out[idx] = do_leaky ? leakyf(v) : v;
}

extern "C" void kernel_launch(void* const* d_in, const int* in_sizes, int n_in,
                              void* d_out, int out_size, void* d_ws, size_t ws_size,
                              hipStream_t stream)
{
    const float* x      = (const float*)d_in[0];
    const int*   ei     = (const int*)  d_in[1];
    const float* ea     = (const float*)d_in[2];
    const float* w1_0   = (const float*)d_in[3];
    const float* b1_0   = (const float*)d_in[4];
    const float* w2_0   = (const float*)d_in[5];
    const float* b2_0   = (const float*)d_in[6];
    const float* root_0 = (const float*)d_in[7];
    const float* bias_0 = (const float*)d_in[8];
    const float* w1_1   = (const float*)d_in[9];
    const float* b1_1   = (const float*)d_in[10];
    const float* w2_1   = (const float*)d_in[11];
    const float* b2_1   = (const float*)d_in[12];
    const float* root_1 = (const float*)d_in[13];
    const float* bias_1 = (const float*)d_in[14];

    const int* esrc = ei;
    const int* edst = ei + NE;

    // ws: w2T0|w2T1 (bf16) | w1T0|w1T1 (bf16) | agg | cnt | x1 (f32)
    unsigned short* w2T0 = (unsigned short*)d_ws;
    unsigned short* w2T1 = w2T0 + HH * HH;
    unsigned short* w1T0 = w2T1 + HH * HH;
    unsigned short* w1T1 = w1T0 + HH * EAD;
    float* agg = (float*)(w1T1 + HH * EAD);
    float* cnt = agg + (size_t)NN * DOUT;
    float* x1  = cnt + NN;
    const size_t ws_need = (size_t)((char*)(x1 + (size_t)NN * DIN) - (char*)d_ws);
    if (ws_size < ws_need) return;  // fail clean (absmax), not a GPU fault

    (void)hipMemsetAsync(agg, 0, ((size_t)NN * DOUT + NN) * sizeof(float), stream);
    prep_kernel<<<HH * HH / 256, 256, 0, stream>>>(w2_0, w2_1, w1_0, w1_1,
                                                   w2T0, w2T1, w1T0, w1T1);

    edge_kernel<1><<<NE / EPB, 256, 0, stream>>>(x, esrc, edst, ea,
                                                 w1T0, b1_0, w2T0, b2_0, agg, cnt);
    finalize_kernel<1><<<(NN * DOUT + 255) / 256, 256, 0, stream>>>(agg, cnt, x,
                                                 root_0, bias_0, x1, 1);
    edge_kernel<0><<<NE / EPB, 256, 0, stream>>>(x1, esrc, edst, ea,
                                                 w1T1, b1_1, w2T1, b2_1, agg, cnt);
    finalize_kernel<0><<<(NN * DOUT + 255) / 256, 256, 0, stream>>>(agg, cnt, x1,
                                                 root_1, bias_1, (float*)d_out, 0);
}